// Round 4
// baseline (278.934 us; speedup 1.0000x reference)
//
#include <hip/hip_runtime.h>
#include <stdint.h>

typedef int v4i __attribute__((ext_vector_type(4)));
typedef float float4_t __attribute__((ext_vector_type(4)));

#define K_DIM 1024
#define N_DIM 1024
#define BM 128
#define BN 128
#define NKT 8  // K-tiles of 128 i8

__device__ __forceinline__ void gload16(const void* g, void* l) {
  __builtin_amdgcn_global_load_lds(
      (const __attribute__((address_space(1))) unsigned int*)g,
      (__attribute__((address_space(3))) unsigned int*)l, 16, 0, 0);
}

#define MFMA_I8 __builtin_amdgcn_mfma_i32_16x16x64_i8

// ---------------------------------------------------------------------------
// Kernel 1: per-token FWHT (== x @ H, H = Sylvester/sqrt(1024)) + 4-bit quant.
// 1 wave/token, 16 f32/lane. Mapping: e = lane*16 + r  ->  contiguous 16B
// loads/stores per lane. Stages: r-bits (1,2,4,8) local; lane-bits via
// shfl_xor with sign-FMA butterflies (exact: fma(+-1,v,p) = p +- v).
// ---------------------------------------------------------------------------
__global__ __launch_bounds__(256) void fwht_quant_kernel(
    const float* __restrict__ x, int8_t* __restrict__ qx,
    float* __restrict__ ascale, int M) {
  const int lane = threadIdx.x & 63;
  const int wid = threadIdx.x >> 6;
  const long token = (long)blockIdx.x * 4 + wid;
  if (token >= M) return;
  const float4_t* xr4 = (const float4_t*)(x + token * K_DIM);

  float v[16];
#pragma unroll
  for (int i = 0; i < 4; ++i) {
    float4_t f = xr4[lane * 4 + i];
#pragma unroll
    for (int c = 0; c < 4; ++c) v[i * 4 + c] = f[c];
  }
  // local stages: element strides 1,2,4,8
#pragma unroll
  for (int s = 1; s <= 8; s <<= 1) {
#pragma unroll
    for (int r = 0; r < 16; ++r)
      if ((r & s) == 0) {
        float a0 = v[r], b0 = v[r | s];
        v[r] = a0 + b0;
        v[r | s] = a0 - b0;
      }
  }
  // cross-lane stages: element strides 16..512 -> lane masks 1..32
#pragma unroll
  for (int m = 1; m <= 32; m <<= 1) {
    const float sg = (lane & m) ? -1.0f : 1.0f;  // hoisted per stage
#pragma unroll
    for (int r = 0; r < 16; ++r) {
      float p = __shfl_xor(v[r], m, 64);
      v[r] = fmaf(sg, v[r], p);
    }
  }
  // absmax on UNnormalized values; fold 1/32 norm into the scale
  float mx = 0.f;
#pragma unroll
  for (int r = 0; r < 16; ++r) mx = fmaxf(mx, fabsf(v[r]));
#pragma unroll
  for (int m = 32; m >= 1; m >>= 1) mx = fmaxf(mx, __shfl_xor(mx, m, 64));
  const float scale = fmaxf(mx * 0.03125f, 1e-5f) * (1.0f / 7.0f);
  if (lane == 0) ascale[token] = scale;
  const float inv = 0.03125f / scale;

  v4i pk;
#pragma unroll
  for (int i = 0; i < 4; ++i) {
    int packed = 0;
#pragma unroll
    for (int c = 0; c < 4; ++c) {
      float q = rintf(v[i * 4 + c] * inv);
      q = fminf(7.f, fmaxf(-8.f, q));
      packed |= ((int)q & 0xff) << (8 * c);
    }
    pk[i] = packed;
  }
  *(v4i*)(qx + token * K_DIM + lane * 16) = pk;  // 16B contiguous/lane
}

// ---------------------------------------------------------------------------
// Kernel 2: per-row ternary weight quantization. 1 wave per row. (unchanged)
// ---------------------------------------------------------------------------
__global__ __launch_bounds__(256) void wquant_kernel(
    const float* __restrict__ w, int8_t* __restrict__ qw,
    float* __restrict__ wscale) {
  const int lane = threadIdx.x & 63;
  const int wid = threadIdx.x >> 6;
  const int row = blockIdx.x * 4 + wid;
  const float* wr = w + (long)row * K_DIM;

  float v[16];
  float s = 0.f;
  const float4_t* wr4 = (const float4_t*)wr;
#pragma unroll
  for (int rr = 0; rr < 4; ++rr) {
    float4_t f = wr4[rr * 64 + lane];
#pragma unroll
    for (int c = 0; c < 4; ++c) {
      v[rr * 4 + c] = f[c];
      s += fabsf(f[c]);
    }
  }
#pragma unroll
  for (int m = 32; m >= 1; m >>= 1) s += __shfl_xor(s, m, 64);
  const float scale = fmaxf(s * (1.0f / 1024.0f), 1e-5f);
  if (lane == 0) wscale[row] = scale;

  int8_t* qr = qw + (long)row * K_DIM;
#pragma unroll
  for (int rr = 0; rr < 4; ++rr) {
    int packed = 0;
#pragma unroll
    for (int c = 0; c < 4; ++c) {
      float n = v[rr * 4 + c] / scale;
      int t = (n > 0.5f) ? 1 : ((n < -0.5f) ? -1 : 0);
      packed |= (t & 0xff) << (8 * c);
    }
    *(int*)(qr + rr * 256 + lane * 4) = packed;
  }
}

// ---------------------------------------------------------------------------
// Kernel 3: int8 GEMM, 128x128 tile, 256 thr (2x2 waves, 64x64/wave).
// - A only in LDS: 2 x 16 KiB double-buffer (chunk-XOR swizzled via
//   inverse-swizzled global source; linear gload_lds dest, rule #21).
// - B (qw, 1 MB, L2-resident) streamed to VGPRs, prefetched 1 K-tile ahead.
// - Counted vmcnt(12) per tile (4 gload_lds + 8 B-loads), never drained;
//   2 raw s_barriers/tile; 8 K-tiles fully unrolled.
// - 32 KiB LDS + <=170 VGPR -> 3 blocks/CU: epilogue overlaps other blocks.
// ---------------------------------------------------------------------------
__global__ __launch_bounds__(256, 3) void gemm_i8_kernel(
    const int8_t* __restrict__ A, const int8_t* __restrict__ B,
    const float* __restrict__ asc, const float* __restrict__ wsc,
    float* __restrict__ C, int M) {
  __shared__ __align__(16) int8_t Al[2][BM * 128];
  const int t = threadIdx.x;
  const int lane = t & 63;
  const int wid = t >> 6;
  const int wm = wid >> 1, wn = wid & 1;
  const int rl = lane & 15, kb = lane >> 4;

  // T1: XCD swizzle. grid = 512*8 = 4096, 4096%8==0. Consecutive swz share bm.
  const int swz = (blockIdx.x & 7) * 512 + (blockIdx.x >> 3);
  const long bm = swz >> 3;  // 0..511
  const int bn = swz & 7;    // 0..7

  // A staging: tile 128 rows x 128B; thread t covers row t>>3 (+32/stmt),
  // slot t&7; global k-chunk inverse-swizzled by row&7 (T2, rule #21).
  const int chunkoff = ((t & 7) ^ ((t >> 3) & 7)) << 4;
  const int8_t* gA = A + (bm * BM + (t >> 3)) * (long)K_DIM + chunkoff;
  // B frags: col = bn*128 + wn*64 + nj*16 + rl; k = kt*128 + ks*64 + kb*16
  const int8_t* gB = B + ((long)bn * BN + wn * 64 + rl) * K_DIM + kb * 16;

  // A-frag read offsets: logical chunk ks*4+kb, phys = ^(rl&7)
  const int arow = (wm * 64 + rl) * 128;
  const int sw0 = ((kb ^ (rl & 7)) << 4);
  const int sw1 = (((4 + kb) ^ (rl & 7)) << 4);

  v4i acc[4][4] = {};
  v4i bb[2][4][2];

#define STAGE_A(buf, koff)                                  \
  gload16(gA + (koff), (buf) + t * 16);                     \
  gload16(gA + 32 * K_DIM + (koff), (buf) + 4096 + t * 16); \
  gload16(gA + 64 * K_DIM + (koff), (buf) + 8192 + t * 16); \
  gload16(gA + 96 * K_DIM + (koff), (buf) + 12288 + t * 16);

  // prologue: stage A0,A1 (8 gload_lds), load B0 (8); wait A0 only.
  STAGE_A(&Al[0][0], 0);
  STAGE_A(&Al[1][0], 128);
#pragma unroll
  for (int nj = 0; nj < 4; ++nj)
#pragma unroll
    for (int ks = 0; ks < 2; ++ks)
      bb[0][nj][ks] = *(const v4i*)(gB + nj * 16 * K_DIM + ks * 64);
  asm volatile("s_waitcnt vmcnt(12)" ::: "memory");
  asm volatile("s_barrier" ::: "memory");

#pragma unroll
  for (int kt = 0; kt < NKT; ++kt) {
    const int p = kt & 1;
    const int8_t* Ab = &Al[p][0];
    v4i a[4][2];
#pragma unroll
    for (int mi = 0; mi < 4; ++mi) {
      a[mi][0] = *(const v4i*)(Ab + arow + mi * 2048 + sw0);
      a[mi][1] = *(const v4i*)(Ab + arow + mi * 2048 + sw1);
    }
    asm volatile("s_barrier" ::: "memory");  // all waves' A-reads in DS pipe
    if (kt < NKT - 2) {
      STAGE_A(&Al[p][0], (kt + 2) * 128);  // overwrite read buffer (safe: >=300cy)
    }
    if (kt < NKT - 1) {
#pragma unroll
      for (int nj = 0; nj < 4; ++nj)
#pragma unroll
        for (int ks = 0; ks < 2; ++ks)
          bb[(kt + 1) & 1][nj][ks] =
              *(const v4i*)(gB + nj * 16 * K_DIM + (kt + 1) * 128 + ks * 64);
    }
    __builtin_amdgcn_s_setprio(1);
#pragma unroll
    for (int ks = 0; ks < 2; ++ks)
#pragma unroll
      for (int nj = 0; nj < 4; ++nj)
#pragma unroll
        for (int mi = 0; mi < 4; ++mi)
          acc[mi][nj] = MFMA_I8(a[mi][ks], bb[p][nj][ks], acc[mi][nj], 0, 0, 0);
    __builtin_amdgcn_s_setprio(0);
    // counted waits: everything issued BEFORE this tile must be retired
    // (incl. A(kt+1) staged at kt-1) before the tile-end barrier.
    if (kt < NKT - 2)
      asm volatile("s_waitcnt vmcnt(12)" ::: "memory");
    else if (kt == NKT - 2)
      asm volatile("s_waitcnt vmcnt(8)" ::: "memory");
    if (kt < NKT - 1) asm volatile("s_barrier" ::: "memory");
  }
#undef STAGE_A

  // epilogue: C/D layout col=lane&15, row=(lane>>4)*4+reg
  const long row0 = bm * BM + wm * 64;
  const int col0 = bn * BN + wn * 64;
  const int lrow = kb * 4;
#pragma unroll
  for (int mi = 0; mi < 4; ++mi) {
    float as[4];
#pragma unroll
    for (int r = 0; r < 4; ++r) as[r] = asc[row0 + mi * 16 + lrow + r];
#pragma unroll
    for (int nj = 0; nj < 4; ++nj) {
      const int col = col0 + nj * 16 + rl;
      const float ws = wsc[col];
#pragma unroll
      for (int r = 0; r < 4; ++r)
        C[(row0 + mi * 16 + lrow + r) * (long)N_DIM + col] =
            (float)acc[mi][nj][r] * as[r] * ws;
    }
  }
}

// ---------------------------------------------------------------------------
extern "C" void kernel_launch(void* const* d_in, const int* in_sizes, int n_in,
                              void* d_out, int out_size, void* d_ws, size_t ws_size,
                              hipStream_t stream) {
  const float* x = (const float*)d_in[0];  // [8,8192,1024] f32
  const float* w = (const float*)d_in[1];  // [1024,1024] f32
  float* out = (float*)d_out;              // [8,8192,1024] f32
  const int M = in_sizes[0] / K_DIM;       // 65536

  int8_t* qx = (int8_t*)d_ws;
  int8_t* qw = qx + (size_t)M * K_DIM;
  float* ascale = (float*)(qw + (size_t)N_DIM * K_DIM);
  float* wscale = ascale + M;

  fwht_quant_kernel<<<(M + 3) / 4, 256, 0, stream>>>(x, qx, ascale, M);
  wquant_kernel<<<N_DIM / 4, 256, 0, stream>>>(w, qw, wscale);
  gemm_i8_kernel<<<(M / BM) * (N_DIM / BN), 256, 0, stream>>>(qx, qw, ascale, wscale, out, M);
}

// Round 5
// 218.378 us; speedup vs baseline: 1.2773x; 1.2773x over previous
//
#include <hip/hip_runtime.h>
#include <stdint.h>

typedef int v4i __attribute__((ext_vector_type(4)));
typedef float float4_t __attribute__((ext_vector_type(4)));

#define K_DIM 1024
#define N_DIM 1024
#define BM 128
#define BN 128
#define BKB 128  // K-step bytes = 2 half-K subtiles of 64B

__device__ __forceinline__ void gload16(const void* g, void* l) {
  __builtin_amdgcn_global_load_lds(
      (const __attribute__((address_space(1))) unsigned int*)g,
      (__attribute__((address_space(3))) unsigned int*)l, 16, 0, 0);
}

#define MFMA_I8 __builtin_amdgcn_mfma_i32_16x16x64_i8

// ---------------------------------------------------------------------------
// Kernel 1: per-token FWHT (== x @ H, H = Sylvester/sqrt(1024)) + 4-bit quant.
// 1 wave/token, 16 f32/lane, mapping e = lane*16 + r (16B contiguous I/O).
// x is read-once -> nontemporal loads (don't evict qx/qw from L2).
// ---------------------------------------------------------------------------
__global__ __launch_bounds__(256) void fwht_quant_kernel(
    const float* __restrict__ x, int8_t* __restrict__ qx,
    float* __restrict__ ascale, int M) {
  const int lane = threadIdx.x & 63;
  const int wid = threadIdx.x >> 6;
  const long token = (long)blockIdx.x * 4 + wid;
  if (token >= M) return;
  const float4_t* xr4 = (const float4_t*)(x + token * K_DIM);

  float v[16];
#pragma unroll
  for (int i = 0; i < 4; ++i) {
    float4_t f = __builtin_nontemporal_load(&xr4[lane * 4 + i]);
#pragma unroll
    for (int c = 0; c < 4; ++c) v[i * 4 + c] = f[c];
  }
  // local stages: element strides 1,2,4,8
#pragma unroll
  for (int s = 1; s <= 8; s <<= 1) {
#pragma unroll
    for (int r = 0; r < 16; ++r)
      if ((r & s) == 0) {
        float a0 = v[r], b0 = v[r | s];
        v[r] = a0 + b0;
        v[r | s] = a0 - b0;
      }
  }
  // cross-lane stages: strides 16..512 -> lane masks 1..32 (sign-FMA, exact)
#pragma unroll
  for (int m = 1; m <= 32; m <<= 1) {
    const float sg = (lane & m) ? -1.0f : 1.0f;
#pragma unroll
    for (int r = 0; r < 16; ++r) {
      float p = __shfl_xor(v[r], m, 64);
      v[r] = fmaf(sg, v[r], p);
    }
  }
  float mx = 0.f;
#pragma unroll
  for (int r = 0; r < 16; ++r) mx = fmaxf(mx, fabsf(v[r]));
#pragma unroll
  for (int m = 32; m >= 1; m >>= 1) mx = fmaxf(mx, __shfl_xor(mx, m, 64));
  const float scale = fmaxf(mx * 0.03125f, 1e-5f) * (1.0f / 7.0f);
  if (lane == 0) ascale[token] = scale;
  const float inv = 0.03125f / scale;

  v4i pk;
#pragma unroll
  for (int i = 0; i < 4; ++i) {
    int packed = 0;
#pragma unroll
    for (int c = 0; c < 4; ++c) {
      float q = rintf(v[i * 4 + c] * inv);
      q = fminf(7.f, fmaxf(-8.f, q));
      packed |= ((int)q & 0xff) << (8 * c);
    }
    pk[i] = packed;
  }
  *(v4i*)(qx + token * K_DIM + lane * 16) = pk;  // cached: GEMM re-reads
}

// ---------------------------------------------------------------------------
// Kernel 2: per-row ternary weight quantization. 1 wave per row.
// ---------------------------------------------------------------------------
__global__ __launch_bounds__(256) void wquant_kernel(
    const float* __restrict__ w, int8_t* __restrict__ qw,
    float* __restrict__ wscale) {
  const int lane = threadIdx.x & 63;
  const int wid = threadIdx.x >> 6;
  const int row = blockIdx.x * 4 + wid;
  const float* wr = w + (long)row * K_DIM;

  float v[16];
  float s = 0.f;
  const float4_t* wr4 = (const float4_t*)wr;
#pragma unroll
  for (int rr = 0; rr < 4; ++rr) {
    float4_t f = wr4[rr * 64 + lane];
#pragma unroll
    for (int c = 0; c < 4; ++c) {
      v[rr * 4 + c] = f[c];
      s += fabsf(f[c]);
    }
  }
#pragma unroll
  for (int m = 32; m >= 1; m >>= 1) s += __shfl_xor(s, m, 64);
  const float scale = fmaxf(s * (1.0f / 1024.0f), 1e-5f);
  if (lane == 0) wscale[row] = scale;

  int8_t* qr = qw + (long)row * K_DIM;
#pragma unroll
  for (int rr = 0; rr < 4; ++rr) {
    int packed = 0;
#pragma unroll
    for (int c = 0; c < 4; ++c) {
      float n = v[rr * 4 + c] / scale;
      int t = (n > 0.5f) ? 1 : ((n < -0.5f) ? -1 : 0);
      packed |= (t & 0xff) << (8 * c);
    }
    *(int*)(qr + rr * 256 + lane * 4) = packed;
  }
}

// ---------------------------------------------------------------------------
// Kernel 3: int8 GEMM, round-2 proven structure: 128x128 tile, BK=128 i8,
// 4 waves (2x2), both operands staged via global_load_lds width-16 into
// [ks2][128 rows][64B] layout (conflict-free staging bijection), 8 K-iters,
// __syncthreads 2-barrier loop, mfma_i32_16x16x64_i8.
// ONE change vs round 2: nontemporal epilogue stores (C never re-read) ->
// no L2 write-allocate (round-4 profile: FETCH +26MB, WRITE 365MB vs 268MB).
// ---------------------------------------------------------------------------
__global__ __launch_bounds__(256) void gemm_i8_kernel(
    const int8_t* __restrict__ A, const int8_t* __restrict__ B,
    const float* __restrict__ asc, const float* __restrict__ wsc,
    float* __restrict__ C, int M) {
  __shared__ int8_t Al[2 * BM * 64];
  __shared__ int8_t Bl[2 * BN * 64];
  const int bn = blockIdx.x & 7;   // 1024/128 = 8 col tiles
  const long bm = blockIdx.x >> 3;
  const int t = threadIdx.x;
  const int lane = t & 63;
  const int wm = (t >> 6) >> 1;    // wave row 0..1
  const int wn = (t >> 6) & 1;     // wave col 0..1

  const int8_t* gA = A + (bm * BM + (t >> 2)) * (long)K_DIM + (t & 3) * 16;
  const int8_t* gB = B + ((long)bn * BN + (t >> 2)) * K_DIM + (t & 3) * 16;

  v4i acc[4][4] = {};
  const int rl = lane & 15;
  const int kb16 = (lane >> 4) * 16;

  for (int ks = 0; ks < K_DIM; ks += BKB) {
    gload16(gA + ks, Al + t * 16);                            // ks2=0 rows 0-63
    gload16(gA + ks + 64 * K_DIM, Al + 4096 + t * 16);        // ks2=0 rows 64-127
    gload16(gA + ks + 64, Al + 8192 + t * 16);                // ks2=1 rows 0-63
    gload16(gA + ks + 64 * K_DIM + 64, Al + 12288 + t * 16);  // ks2=1 rows 64-127
    gload16(gB + ks, Bl + t * 16);
    gload16(gB + ks + 64 * K_DIM, Bl + 4096 + t * 16);
    gload16(gB + ks + 64, Bl + 8192 + t * 16);
    gload16(gB + ks + 64 * K_DIM + 64, Bl + 12288 + t * 16);
    __syncthreads();

#pragma unroll
    for (int ks2 = 0; ks2 < 2; ++ks2) {
      v4i a[4], b[4];
#pragma unroll
      for (int i = 0; i < 4; ++i)
        a[i] = *(const v4i*)(Al + ks2 * 8192 + (wm * 64 + i * 16 + rl) * 64 + kb16);
#pragma unroll
      for (int j = 0; j < 4; ++j)
        b[j] = *(const v4i*)(Bl + ks2 * 8192 + (wn * 64 + j * 16 + rl) * 64 + kb16);
#pragma unroll
      for (int i = 0; i < 4; ++i)
#pragma unroll
        for (int j = 0; j < 4; ++j)
          acc[i][j] = MFMA_I8(a[i], b[j], acc[i][j], 0, 0, 0);
    }
    __syncthreads();
  }

  // epilogue: C/D layout col=lane&15, row=(lane>>4)*4+reg; nt stores
  const long row0 = bm * BM + wm * 64;
  const int col0 = bn * BN + wn * 64;
  const int lrow = (lane >> 4) * 4;
  const int lcol = lane & 15;
#pragma unroll
  for (int i = 0; i < 4; ++i) {
    float as[4];
#pragma unroll
    for (int r = 0; r < 4; ++r) as[r] = asc[row0 + i * 16 + lrow + r];
#pragma unroll
    for (int j = 0; j < 4; ++j) {
      const int col = col0 + j * 16 + lcol;
      const float ws = wsc[col];
#pragma unroll
      for (int r = 0; r < 4; ++r)
        __builtin_nontemporal_store(
            (float)acc[i][j][r] * as[r] * ws,
            &C[(row0 + i * 16 + lrow + r) * (long)N_DIM + col]);
    }
  }
}

// ---------------------------------------------------------------------------
extern "C" void kernel_launch(void* const* d_in, const int* in_sizes, int n_in,
                              void* d_out, int out_size, void* d_ws, size_t ws_size,
                              hipStream_t stream) {
  const float* x = (const float*)d_in[0];  // [8,8192,1024] f32
  const float* w = (const float*)d_in[1];  // [1024,1024] f32
  float* out = (float*)d_out;              // [8,8192,1024] f32
  const int M = in_sizes[0] / K_DIM;       // 65536

  int8_t* qx = (int8_t*)d_ws;
  int8_t* qw = qx + (size_t)M * K_DIM;
  float* ascale = (float*)(qw + (size_t)N_DIM * K_DIM);
  float* wscale = ascale + M;

  fwht_quant_kernel<<<(M + 3) / 4, 256, 0, stream>>>(x, qx, ascale, M);
  wquant_kernel<<<N_DIM / 4, 256, 0, stream>>>(w, qw, wscale);
  gemm_i8_kernel<<<(M / BM) * (N_DIM / BN), 256, 0, stream>>>(qx, qw, ascale, wscale, out, M);
}

// Round 6
// 210.055 us; speedup vs baseline: 1.3279x; 1.0396x over previous
//
#include <hip/hip_runtime.h>
#include <stdint.h>

typedef int v4i __attribute__((ext_vector_type(4)));
typedef float float4_t __attribute__((ext_vector_type(4)));

#define K_DIM 1024
#define N_DIM 1024
#define BM 128
#define BN 128
#define BKB 128  // K-step bytes = 2 half-K subtiles of 64B

__device__ __forceinline__ void gload16(const void* g, void* l) {
  __builtin_amdgcn_global_load_lds(
      (const __attribute__((address_space(1))) unsigned int*)g,
      (__attribute__((address_space(3))) unsigned int*)l, 16, 0, 0);
}

#define MFMA_I8 __builtin_amdgcn_mfma_i32_16x16x64_i8

// ---------------------------------------------------------------------------
// Kernel 1: per-token FWHT (== x @ H, H = Sylvester/sqrt(1024)) + 4-bit quant.
// 1 wave/token, 16 f32/lane, mapping e = lane*16 + r (16B contiguous I/O).
// Plain loads (nt-load regressed in R5).
// ---------------------------------------------------------------------------
__global__ __launch_bounds__(256) void fwht_quant_kernel(
    const float* __restrict__ x, int8_t* __restrict__ qx,
    float* __restrict__ ascale, int M) {
  const int lane = threadIdx.x & 63;
  const int wid = threadIdx.x >> 6;
  const long token = (long)blockIdx.x * 4 + wid;
  if (token >= M) return;
  const float4_t* xr4 = (const float4_t*)(x + token * K_DIM);

  float v[16];
#pragma unroll
  for (int i = 0; i < 4; ++i) {
    float4_t f = xr4[lane * 4 + i];
#pragma unroll
    for (int c = 0; c < 4; ++c) v[i * 4 + c] = f[c];
  }
  // local stages: element strides 1,2,4,8
#pragma unroll
  for (int s = 1; s <= 8; s <<= 1) {
#pragma unroll
    for (int r = 0; r < 16; ++r)
      if ((r & s) == 0) {
        float a0 = v[r], b0 = v[r | s];
        v[r] = a0 + b0;
        v[r | s] = a0 - b0;
      }
  }
  // cross-lane stages: strides 16..512 -> lane masks 1..32 (sign-FMA, exact)
#pragma unroll
  for (int m = 1; m <= 32; m <<= 1) {
    const float sg = (lane & m) ? -1.0f : 1.0f;
#pragma unroll
    for (int r = 0; r < 16; ++r) {
      float p = __shfl_xor(v[r], m, 64);
      v[r] = fmaf(sg, v[r], p);
    }
  }
  float mx = 0.f;
#pragma unroll
  for (int r = 0; r < 16; ++r) mx = fmaxf(mx, fabsf(v[r]));
#pragma unroll
  for (int m = 32; m >= 1; m >>= 1) mx = fmaxf(mx, __shfl_xor(mx, m, 64));
  const float scale = fmaxf(mx * 0.03125f, 1e-5f) * (1.0f / 7.0f);
  if (lane == 0) ascale[token] = scale;
  const float inv = 0.03125f / scale;

  v4i pk;
#pragma unroll
  for (int i = 0; i < 4; ++i) {
    int packed = 0;
#pragma unroll
    for (int c = 0; c < 4; ++c) {
      float q = rintf(v[i * 4 + c] * inv);
      q = fminf(7.f, fmaxf(-8.f, q));
      packed |= ((int)q & 0xff) << (8 * c);
    }
    pk[i] = packed;
  }
  *(v4i*)(qx + token * K_DIM + lane * 16) = pk;
}

// ---------------------------------------------------------------------------
// Kernel 2: per-row ternary weight quantization. 1 wave per row.
// ---------------------------------------------------------------------------
__global__ __launch_bounds__(256) void wquant_kernel(
    const float* __restrict__ w, int8_t* __restrict__ qw,
    float* __restrict__ wscale) {
  const int lane = threadIdx.x & 63;
  const int wid = threadIdx.x >> 6;
  const int row = blockIdx.x * 4 + wid;
  const float* wr = w + (long)row * K_DIM;

  float v[16];
  float s = 0.f;
  const float4_t* wr4 = (const float4_t*)wr;
#pragma unroll
  for (int rr = 0; rr < 4; ++rr) {
    float4_t f = wr4[rr * 64 + lane];
#pragma unroll
    for (int c = 0; c < 4; ++c) {
      v[rr * 4 + c] = f[c];
      s += fabsf(f[c]);
    }
  }
#pragma unroll
  for (int m = 32; m >= 1; m >>= 1) s += __shfl_xor(s, m, 64);
  const float scale = fmaxf(s * (1.0f / 1024.0f), 1e-5f);
  if (lane == 0) wscale[row] = scale;

  int8_t* qr = qw + (long)row * K_DIM;
#pragma unroll
  for (int rr = 0; rr < 4; ++rr) {
    int packed = 0;
#pragma unroll
    for (int c = 0; c < 4; ++c) {
      float n = v[rr * 4 + c] / scale;
      int t = (n > 0.5f) ? 1 : ((n < -0.5f) ? -1 : 0);
      packed |= (t & 0xff) << (8 * c);
    }
    *(int*)(qr + rr * 256 + lane * 4) = packed;
  }
}

// ---------------------------------------------------------------------------
// Kernel 3: int8 GEMM. K-loop = round-2 proven structure (128x128 tile,
// BK=128 i8, 4 waves, gload_lds width-16, [ks2][128][64] layout, 8 iters,
// 2-barrier). NEW: LDS-transpose epilogue — deposit scaled acc into the
// (now free) 32 KiB staging LDS, re-read row-major, store float4 where 32
// consecutive lanes cover 512 contiguous B = 4 full aligned 128-B lines ->
// L2 write-combines like fillBuffer (7 TB/s, zero write-allocate fetch).
// nt on FULL lines only.
// ---------------------------------------------------------------------------
__global__ __launch_bounds__(256) void gemm_i8_kernel(
    const int8_t* __restrict__ A, const int8_t* __restrict__ B,
    const float* __restrict__ asc, const float* __restrict__ wsc,
    float* __restrict__ C, int M) {
  __shared__ __align__(16) int8_t smem[32768];
  int8_t* Al = smem;           // 16 KB
  int8_t* Bl = smem + 16384;   // 16 KB
  float* tr = (float*)smem;    // epilogue: 64 rows x 128 cols f32 = 32 KB

  const int bn = blockIdx.x & 7;
  const long bm = blockIdx.x >> 3;
  const int t = threadIdx.x;
  const int lane = t & 63;
  const int wm = (t >> 6) >> 1;
  const int wn = (t >> 6) & 1;

  const int8_t* gA = A + (bm * BM + (t >> 2)) * (long)K_DIM + (t & 3) * 16;
  const int8_t* gB = B + ((long)bn * BN + (t >> 2)) * K_DIM + (t & 3) * 16;

  v4i acc[4][4] = {};
  const int rl = lane & 15;
  const int kb = lane >> 4;
  const int kb16 = kb * 16;

  for (int ks = 0; ks < K_DIM; ks += BKB) {
    gload16(gA + ks, Al + t * 16);
    gload16(gA + ks + 64 * K_DIM, Al + 4096 + t * 16);
    gload16(gA + ks + 64, Al + 8192 + t * 16);
    gload16(gA + ks + 64 * K_DIM + 64, Al + 12288 + t * 16);
    gload16(gB + ks, Bl + t * 16);
    gload16(gB + ks + 64 * K_DIM, Bl + 4096 + t * 16);
    gload16(gB + ks + 64, Bl + 8192 + t * 16);
    gload16(gB + ks + 64 * K_DIM + 64, Bl + 12288 + t * 16);
    __syncthreads();

#pragma unroll
    for (int ks2 = 0; ks2 < 2; ++ks2) {
      v4i a[4], b[4];
#pragma unroll
      for (int i = 0; i < 4; ++i)
        a[i] = *(const v4i*)(Al + ks2 * 8192 + (wm * 64 + i * 16 + rl) * 64 + kb16);
#pragma unroll
      for (int j = 0; j < 4; ++j)
        b[j] = *(const v4i*)(Bl + ks2 * 8192 + (wn * 64 + j * 16 + rl) * 64 + kb16);
#pragma unroll
      for (int i = 0; i < 4; ++i)
#pragma unroll
        for (int j = 0; j < 4; ++j)
          acc[i][j] = MFMA_I8(a[i], b[j], acc[i][j], 0, 0, 0);
    }
    __syncthreads();
  }

  // ---- LDS-transpose epilogue, 2 chunks of 64 rows ----
  const long rowg0 = bm * BM + wm * 64;   // this wave's global row base
  const int colg0 = bn * BN + wn * 64;    // this wave's global col base
#pragma unroll
  for (int c = 0; c < 2; ++c) {
    if (wm == c) {
      // deposit scaled acc: local row = i*16 + kb*4 + r (0..63), col = wn*64+j*16+rl
#pragma unroll
      for (int i = 0; i < 4; ++i) {
        float as[4];
#pragma unroll
        for (int r = 0; r < 4; ++r) as[r] = asc[rowg0 + i * 16 + kb * 4 + r];
#pragma unroll
        for (int j = 0; j < 4; ++j) {
          const float ws = wsc[colg0 + j * 16 + rl];
#pragma unroll
          for (int r = 0; r < 4; ++r)
            tr[(i * 16 + kb * 4 + r) * 128 + wn * 64 + j * 16 + rl] =
                (float)acc[i][j][r] * as[r] * ws;
        }
      }
    }
    __syncthreads();
    // all 256 threads: 8 float4 nt stores; lanes 0-31 cover one 512B row seg
#pragma unroll
    for (int it = 0; it < 8; ++it) {
      const int idx = t + it * 256;        // 0..2047
      const int rl2 = idx >> 5;            // local row 0..63
      const int c4 = (idx & 31) * 4;       // col in floats
      const float4_t val = *(const float4_t*)(tr + rl2 * 128 + c4);
      __builtin_nontemporal_store(
          val, (float4_t*)(C + (bm * BM + c * 64 + rl2) * (long)N_DIM + bn * BN + c4));
    }
    __syncthreads();
  }
}

// ---------------------------------------------------------------------------
extern "C" void kernel_launch(void* const* d_in, const int* in_sizes, int n_in,
                              void* d_out, int out_size, void* d_ws, size_t ws_size,
                              hipStream_t stream) {
  const float* x = (const float*)d_in[0];  // [8,8192,1024] f32
  const float* w = (const float*)d_in[1];  // [1024,1024] f32
  float* out = (float*)d_out;              // [8,8192,1024] f32
  const int M = in_sizes[0] / K_DIM;       // 65536

  int8_t* qx = (int8_t*)d_ws;
  int8_t* qw = qx + (size_t)M * K_DIM;
  float* ascale = (float*)(qw + (size_t)N_DIM * K_DIM);
  float* wscale = ascale + M;

  fwht_quant_kernel<<<(M + 3) / 4, 256, 0, stream>>>(x, qx, ascale, M);
  wquant_kernel<<<N_DIM / 4, 256, 0, stream>>>(w, qw, wscale);
  gemm_i8_kernel<<<(M / BM) * (N_DIM / BN), 256, 0, stream>>>(qx, qw, ascale, wscale, out, M);
}

// Round 7
// 172.826 us; speedup vs baseline: 1.6140x; 1.2154x over previous
//
#include <hip/hip_runtime.h>
#include <stdint.h>

typedef int v4i __attribute__((ext_vector_type(4)));
typedef float float4_t __attribute__((ext_vector_type(4)));

#define K_DIM 1024
#define N_DIM 1024
#define BM 128
#define BN 128

__device__ __forceinline__ void gload16(const void* g, void* l) {
  __builtin_amdgcn_global_load_lds(
      (const __attribute__((address_space(1))) unsigned int*)g,
      (__attribute__((address_space(3))) unsigned int*)l, 16, 0, 0);
}

#define MFMA_I8 __builtin_amdgcn_mfma_i32_16x16x64_i8

// ---------------------------------------------------------------------------
// Kernel 1: per-token FWHT (== x @ H, H = Sylvester/sqrt(1024)) + 4-bit quant.
// 1 wave/token, 16 f32/lane, mapping e = lane*16 + r. (unchanged from R6)
// ---------------------------------------------------------------------------
__global__ __launch_bounds__(256) void fwht_quant_kernel(
    const float* __restrict__ x, int8_t* __restrict__ qx,
    float* __restrict__ ascale, int M) {
  const int lane = threadIdx.x & 63;
  const int wid = threadIdx.x >> 6;
  const long token = (long)blockIdx.x * 4 + wid;
  if (token >= M) return;
  const float4_t* xr4 = (const float4_t*)(x + token * K_DIM);

  float v[16];
#pragma unroll
  for (int i = 0; i < 4; ++i) {
    float4_t f = xr4[lane * 4 + i];
#pragma unroll
    for (int c = 0; c < 4; ++c) v[i * 4 + c] = f[c];
  }
#pragma unroll
  for (int s = 1; s <= 8; s <<= 1) {
#pragma unroll
    for (int r = 0; r < 16; ++r)
      if ((r & s) == 0) {
        float a0 = v[r], b0 = v[r | s];
        v[r] = a0 + b0;
        v[r | s] = a0 - b0;
      }
  }
#pragma unroll
  for (int m = 1; m <= 32; m <<= 1) {
    const float sg = (lane & m) ? -1.0f : 1.0f;
#pragma unroll
    for (int r = 0; r < 16; ++r) {
      float p = __shfl_xor(v[r], m, 64);
      v[r] = fmaf(sg, v[r], p);
    }
  }
  float mx = 0.f;
#pragma unroll
  for (int r = 0; r < 16; ++r) mx = fmaxf(mx, fabsf(v[r]));
#pragma unroll
  for (int m = 32; m >= 1; m >>= 1) mx = fmaxf(mx, __shfl_xor(mx, m, 64));
  const float scale = fmaxf(mx * 0.03125f, 1e-5f) * (1.0f / 7.0f);
  if (lane == 0) ascale[token] = scale;
  const float inv = 0.03125f / scale;

  v4i pk;
#pragma unroll
  for (int i = 0; i < 4; ++i) {
    int packed = 0;
#pragma unroll
    for (int c = 0; c < 4; ++c) {
      float q = rintf(v[i * 4 + c] * inv);
      q = fminf(7.f, fmaxf(-8.f, q));
      packed |= ((int)q & 0xff) << (8 * c);
    }
    pk[i] = packed;
  }
  *(v4i*)(qx + token * K_DIM + lane * 16) = pk;
}

// ---------------------------------------------------------------------------
// Kernel 2: per-row ternary weight quantization. 1 wave per row. (unchanged)
// ---------------------------------------------------------------------------
__global__ __launch_bounds__(256) void wquant_kernel(
    const float* __restrict__ w, int8_t* __restrict__ qw,
    float* __restrict__ wscale) {
  const int lane = threadIdx.x & 63;
  const int wid = threadIdx.x >> 6;
  const int row = blockIdx.x * 4 + wid;
  const float* wr = w + (long)row * K_DIM;

  float v[16];
  float s = 0.f;
  const float4_t* wr4 = (const float4_t*)wr;
#pragma unroll
  for (int rr = 0; rr < 4; ++rr) {
    float4_t f = wr4[rr * 64 + lane];
#pragma unroll
    for (int c = 0; c < 4; ++c) {
      v[rr * 4 + c] = f[c];
      s += fabsf(f[c]);
    }
  }
#pragma unroll
  for (int m = 32; m >= 1; m >>= 1) s += __shfl_xor(s, m, 64);
  const float scale = fmaxf(s * (1.0f / 1024.0f), 1e-5f);
  if (lane == 0) wscale[row] = scale;

  int8_t* qr = qw + (long)row * K_DIM;
#pragma unroll
  for (int rr = 0; rr < 4; ++rr) {
    int packed = 0;
#pragma unroll
    for (int c = 0; c < 4; ++c) {
      float n = v[rr * 4 + c] / scale;
      int t = (n > 0.5f) ? 1 : ((n < -0.5f) ? -1 : 0);
      packed |= (t & 0xff) << (8 * c);
    }
    *(int*)(qr + rr * 256 + lane * 4) = packed;
  }
}

// ---------------------------------------------------------------------------
// Kernel 3: int8 GEMM, 128x128 tile, BK=128, 4 waves, 2-barrier loop.
// R7 changes vs R6 (each targets a measured counter):
//  - T1 XCD swizzle: all 8 bn-blocks of one bm land on the SAME XCD ->
//    A-tile fetched once per XCD L2 (R6: FETCH 265MB = 4x ideal).
//  - LDS layout [128 rows][128B] with chunk-XOR swizzle for BOTH operands
//    (R4's A-path: measured 0 bank conflicts). Staged via inverse-swizzled
//    global source, linear gload_lds dest (rule #21).
//  - Epilogue tr buffer padded to 132 f32/row (deposit 4-way -> 2-way=free).
// ---------------------------------------------------------------------------
__global__ __launch_bounds__(256) void gemm_i8_kernel(
    const int8_t* __restrict__ A, const int8_t* __restrict__ B,
    const float* __restrict__ asc, const float* __restrict__ wsc,
    float* __restrict__ C, int M) {
  __shared__ __align__(16) int8_t smem[34816];  // staging 32KB; epilogue 33792B
  int8_t* Al = smem;          // [128][128]
  int8_t* Bl = smem + 16384;  // [128][128]
  float* tr = (float*)smem;   // epilogue: 64 rows x 132 f32 (padded)

  const int t = threadIdx.x;
  const int lane = t & 63;
  const int wm = (t >> 6) >> 1;
  const int wn = (t >> 6) & 1;
  const int rl = lane & 15;
  const int kb = lane >> 4;

  // T1: XCD swizzle. grid=4096 (4096%8==0). XCD x gets swz in [x*512,x*512+511]
  // -> bm chunk of 64 with bn varying fastest: A-tile reused 8x within one L2.
  const int swz = ((int)blockIdx.x & 7) * 512 + ((int)blockIdx.x >> 3);
  const long bm = swz >> 3;  // 0..511
  const int bn = swz & 7;    // 0..7

  // staging: stmt s covers rows s*32 + (t>>3), phys slot t&7 holds logical
  // chunk (t&7)^(row&7); row&7 = (t>>3)&7. LDS dest linear: row*128+(t&7)*16.
  const int chunkoff = (((t & 7) ^ ((t >> 3) & 7)) << 4);
  const int8_t* gA = A + (bm * BM + (t >> 3)) * (long)K_DIM + chunkoff;
  const int8_t* gB = B + ((long)bn * BN + (t >> 3)) * K_DIM + chunkoff;

  // frag reads: logical chunk ks2*4+kb at row (..+rl) -> phys ^(rl&7)
  const int sw0 = ((kb ^ (rl & 7)) << 4);
  const int sw1 = (((4 + kb) ^ (rl & 7)) << 4);
  const int arow = (wm * 64 + rl) * 128;
  const int brow = (wn * 64 + rl) * 128;

  v4i acc[4][4] = {};

  for (int ks = 0; ks < K_DIM; ks += 128) {
    gload16(gA + ks, Al + t * 16);
    gload16(gA + ks + 32 * K_DIM, Al + 4096 + t * 16);
    gload16(gA + ks + 64 * K_DIM, Al + 8192 + t * 16);
    gload16(gA + ks + 96 * K_DIM, Al + 12288 + t * 16);
    gload16(gB + ks, Bl + t * 16);
    gload16(gB + ks + 32 * K_DIM, Bl + 4096 + t * 16);
    gload16(gB + ks + 64 * K_DIM, Bl + 8192 + t * 16);
    gload16(gB + ks + 96 * K_DIM, Bl + 12288 + t * 16);
    __syncthreads();

#pragma unroll
    for (int ks2 = 0; ks2 < 2; ++ks2) {
      const int sw = ks2 ? sw1 : sw0;
      v4i a[4], b[4];
#pragma unroll
      for (int i = 0; i < 4; ++i)
        a[i] = *(const v4i*)(Al + arow + i * 2048 + sw);
#pragma unroll
      for (int j = 0; j < 4; ++j)
        b[j] = *(const v4i*)(Bl + brow + j * 2048 + sw);
#pragma unroll
      for (int i = 0; i < 4; ++i)
#pragma unroll
        for (int j = 0; j < 4; ++j)
          acc[i][j] = MFMA_I8(a[i], b[j], acc[i][j], 0, 0, 0);
    }
    __syncthreads();
  }

  // ---- LDS-transpose epilogue, 2 chunks of 64 rows, tr stride 132 ----
  const long rowg0 = bm * BM + wm * 64;
  const int colg0 = bn * BN + wn * 64;
#pragma unroll
  for (int c = 0; c < 2; ++c) {
    if (wm == c) {
#pragma unroll
      for (int i = 0; i < 4; ++i) {
        float as[4];
#pragma unroll
        for (int r = 0; r < 4; ++r) as[r] = asc[rowg0 + i * 16 + kb * 4 + r];
#pragma unroll
        for (int j = 0; j < 4; ++j) {
          const float ws = wsc[colg0 + j * 16 + rl];
#pragma unroll
          for (int r = 0; r < 4; ++r)
            tr[(i * 16 + kb * 4 + r) * 132 + wn * 64 + j * 16 + rl] =
                (float)acc[i][j][r] * as[r] * ws;
        }
      }
    }
    __syncthreads();
    // 256 threads x 8 float4 nt stores: 32 lanes cover 512B = 4 full lines
#pragma unroll
    for (int it = 0; it < 8; ++it) {
      const int idx = t + it * 256;  // 0..2047
      const int rl2 = idx >> 5;      // local row 0..63
      const int c4 = (idx & 31) * 4; // col in floats
      const float4_t val = *(const float4_t*)(tr + rl2 * 132 + c4);
      __builtin_nontemporal_store(
          val, (float4_t*)(C + (bm * BM + c * 64 + rl2) * (long)N_DIM + bn * BN + c4));
    }
    __syncthreads();
  }
}

// ---------------------------------------------------------------------------
extern "C" void kernel_launch(void* const* d_in, const int* in_sizes, int n_in,
                              void* d_out, int out_size, void* d_ws, size_t ws_size,
                              hipStream_t stream) {
  const float* x = (const float*)d_in[0];  // [8,8192,1024] f32
  const float* w = (const float*)d_in[1];  // [1024,1024] f32
  float* out = (float*)d_out;              // [8,8192,1024] f32
  const int M = in_sizes[0] / K_DIM;       // 65536

  int8_t* qx = (int8_t*)d_ws;
  int8_t* qw = qx + (size_t)M * K_DIM;
  float* ascale = (float*)(qw + (size_t)N_DIM * K_DIM);
  float* wscale = ascale + M;

  fwht_quant_kernel<<<(M + 3) / 4, 256, 0, stream>>>(x, qx, ascale, M);
  wquant_kernel<<<N_DIM / 4, 256, 0, stream>>>(w, qw, wscale);
  gemm_i8_kernel<<<(M / BM) * (N_DIM / BN), 256, 0, stream>>>(qx, qw, ascale, wscale, out, M);
}

// Round 8
// 167.320 us; speedup vs baseline: 1.6671x; 1.0329x over previous
//
#include <hip/hip_runtime.h>
#include <stdint.h>

typedef int v4i __attribute__((ext_vector_type(4)));
typedef float float4_t __attribute__((ext_vector_type(4)));

#define K_DIM 1024
#define N_DIM 1024
#define BM 128
#define BN 128

__device__ __forceinline__ void gload16(const void* g, void* l) {
  __builtin_amdgcn_global_load_lds(
      (const __attribute__((address_space(1))) unsigned int*)g,
      (__attribute__((address_space(3))) unsigned int*)l, 16, 0, 0);
}

#define MFMA_I8 __builtin_amdgcn_mfma_i32_16x16x64_i8

// ---------------------------------------------------------------------------
// Kernel 1: per-token FWHT (== x @ H, H = Sylvester/sqrt(1024)) + 4-bit quant.
// 1 wave/token, 16 f32/lane, mapping e = lane*16 + r. (unchanged from R7)
// ---------------------------------------------------------------------------
__global__ __launch_bounds__(256) void fwht_quant_kernel(
    const float* __restrict__ x, int8_t* __restrict__ qx,
    float* __restrict__ ascale, int M) {
  const int lane = threadIdx.x & 63;
  const int wid = threadIdx.x >> 6;
  const long token = (long)blockIdx.x * 4 + wid;
  if (token >= M) return;
  const float4_t* xr4 = (const float4_t*)(x + token * K_DIM);

  float v[16];
#pragma unroll
  for (int i = 0; i < 4; ++i) {
    float4_t f = xr4[lane * 4 + i];
#pragma unroll
    for (int c = 0; c < 4; ++c) v[i * 4 + c] = f[c];
  }
#pragma unroll
  for (int s = 1; s <= 8; s <<= 1) {
#pragma unroll
    for (int r = 0; r < 16; ++r)
      if ((r & s) == 0) {
        float a0 = v[r], b0 = v[r | s];
        v[r] = a0 + b0;
        v[r | s] = a0 - b0;
      }
  }
#pragma unroll
  for (int m = 1; m <= 32; m <<= 1) {
    const float sg = (lane & m) ? -1.0f : 1.0f;
#pragma unroll
    for (int r = 0; r < 16; ++r) {
      float p = __shfl_xor(v[r], m, 64);
      v[r] = fmaf(sg, v[r], p);
    }
  }
  float mx = 0.f;
#pragma unroll
  for (int r = 0; r < 16; ++r) mx = fmaxf(mx, fabsf(v[r]));
#pragma unroll
  for (int m = 32; m >= 1; m >>= 1) mx = fmaxf(mx, __shfl_xor(mx, m, 64));
  const float scale = fmaxf(mx * 0.03125f, 1e-5f) * (1.0f / 7.0f);
  if (lane == 0) ascale[token] = scale;
  const float inv = 0.03125f / scale;

  v4i pk;
#pragma unroll
  for (int i = 0; i < 4; ++i) {
    int packed = 0;
#pragma unroll
    for (int c = 0; c < 4; ++c) {
      float q = rintf(v[i * 4 + c] * inv);
      q = fminf(7.f, fmaxf(-8.f, q));
      packed |= ((int)q & 0xff) << (8 * c);
    }
    pk[i] = packed;
  }
  *(v4i*)(qx + token * K_DIM + lane * 16) = pk;
}

// ---------------------------------------------------------------------------
// Kernel 2: per-row ternary weight quantization. 1 wave per row. (unchanged)
// ---------------------------------------------------------------------------
__global__ __launch_bounds__(256) void wquant_kernel(
    const float* __restrict__ w, int8_t* __restrict__ qw,
    float* __restrict__ wscale) {
  const int lane = threadIdx.x & 63;
  const int wid = threadIdx.x >> 6;
  const int row = blockIdx.x * 4 + wid;
  const float* wr = w + (long)row * K_DIM;

  float v[16];
  float s = 0.f;
  const float4_t* wr4 = (const float4_t*)wr;
#pragma unroll
  for (int rr = 0; rr < 4; ++rr) {
    float4_t f = wr4[rr * 64 + lane];
#pragma unroll
    for (int c = 0; c < 4; ++c) {
      v[rr * 4 + c] = f[c];
      s += fabsf(f[c]);
    }
  }
#pragma unroll
  for (int m = 32; m >= 1; m >>= 1) s += __shfl_xor(s, m, 64);
  const float scale = fmaxf(s * (1.0f / 1024.0f), 1e-5f);
  if (lane == 0) wscale[row] = scale;

  int8_t* qr = qw + (long)row * K_DIM;
#pragma unroll
  for (int rr = 0; rr < 4; ++rr) {
    int packed = 0;
#pragma unroll
    for (int c = 0; c < 4; ++c) {
      float n = v[rr * 4 + c] / scale;
      int t = (n > 0.5f) ? 1 : ((n < -0.5f) ? -1 : 0);
      packed |= (t & 0xff) << (8 * c);
    }
    *(int*)(qr + rr * 256 + lane * 4) = packed;
  }
}

// ---------------------------------------------------------------------------
// Kernel 3: int8 GEMM, 128x128 tile, BK=128, 4 waves.
// R8 change vs R7 (one variable): 2-phase DOUBLE-BUFFERED K-loop —
// STAGE(next tile) issued BEFORE compute(current), single __syncthreads per
// tile at the end. The barrier-drain then overlaps ~800 cyc of ds_read+MFMA
// instead of serializing the full staging latency every tile (R7 structure:
// stage -> sync -> compute exposed ~500 cyc/tile).
// Kept from R7 (proven): T1 XCD swizzle (FETCH 265->~80MB), chunk-XOR LDS
// swizzle both operands (conflicts 1e7 -> 0), LDS-transpose epilogue with
// full-line float4 nt stores (WRITE 365->262MB), tr stride 132.
// LDS: 2 x 32 KB staging (epilogue aliases buffer 0) -> 2 blocks/CU.
// ---------------------------------------------------------------------------
__global__ __launch_bounds__(256) void gemm_i8_kernel(
    const int8_t* __restrict__ A, const int8_t* __restrict__ B,
    const float* __restrict__ asc, const float* __restrict__ wsc,
    float* __restrict__ C, int M) {
  __shared__ __align__(16) int8_t smem[2][32768];  // [p]: A 16KB | B 16KB
  float* tr = (float*)smem;  // epilogue: 64 rows x 132 f32 = 33792 B

  const int t = threadIdx.x;
  const int lane = t & 63;
  const int wm = (t >> 6) >> 1;
  const int wn = (t >> 6) & 1;
  const int rl = lane & 15;
  const int kb = lane >> 4;

  // T1: XCD swizzle. grid=4096 (%8==0). XCD x gets swz [x*512, x*512+511]:
  // bm chunk of 64 with bn fastest -> A-tile reused 8x within one XCD L2.
  const int swz = ((int)blockIdx.x & 7) * 512 + ((int)blockIdx.x >> 3);
  const long bm = swz >> 3;  // 0..511
  const int bn = swz & 7;    // 0..7

  // staging: stmt s covers rows s*32 + (t>>3); phys slot t&7 holds logical
  // chunk (t&7)^(row&7). LDS dest linear (rule #21).
  const int chunkoff = (((t & 7) ^ ((t >> 3) & 7)) << 4);
  const int8_t* gA = A + (bm * BM + (t >> 3)) * (long)K_DIM + chunkoff;
  const int8_t* gB = B + ((long)bn * BN + (t >> 3)) * K_DIM + chunkoff;

  // frag reads: logical chunk ks2*4+kb at row (..+rl) -> phys ^(rl&7)
  const int sw0 = ((kb ^ (rl & 7)) << 4);
  const int sw1 = (((4 + kb) ^ (rl & 7)) << 4);
  const int arow = (wm * 64 + rl) * 128;
  const int brow = (wn * 64 + rl) * 128;

  v4i acc[4][4] = {};

#define STAGE(p, ks)                                      \
  gload16(gA + (ks), smem[p] + t * 16);                   \
  gload16(gA + (ks) + 32 * K_DIM, smem[p] + 4096 + t * 16);  \
  gload16(gA + (ks) + 64 * K_DIM, smem[p] + 8192 + t * 16);  \
  gload16(gA + (ks) + 96 * K_DIM, smem[p] + 12288 + t * 16); \
  gload16(gB + (ks), smem[p] + 16384 + t * 16);              \
  gload16(gB + (ks) + 32 * K_DIM, smem[p] + 20480 + t * 16); \
  gload16(gB + (ks) + 64 * K_DIM, smem[p] + 24576 + t * 16); \
  gload16(gB + (ks) + 96 * K_DIM, smem[p] + 28672 + t * 16);

  STAGE(0, 0);
  __syncthreads();

#pragma unroll
  for (int kt = 0; kt < 8; ++kt) {
    const int p = kt & 1;
    if (kt < 7) {
      STAGE(p ^ 1, (kt + 1) * 128);  // prefetch next tile; latency hides
    }                                // under this tile's ds_read+MFMA
    const int8_t* Al = smem[p];
    const int8_t* Bl = smem[p] + 16384;
#pragma unroll
    for (int ks2 = 0; ks2 < 2; ++ks2) {
      const int sw = ks2 ? sw1 : sw0;
      v4i a[4], b[4];
#pragma unroll
      for (int i = 0; i < 4; ++i)
        a[i] = *(const v4i*)(Al + arow + i * 2048 + sw);
#pragma unroll
      for (int j = 0; j < 4; ++j)
        b[j] = *(const v4i*)(Bl + brow + j * 2048 + sw);
#pragma unroll
      for (int i = 0; i < 4; ++i)
#pragma unroll
        for (int j = 0; j < 4; ++j)
          acc[i][j] = MFMA_I8(a[i], b[j], acc[i][j], 0, 0, 0);
    }
    // vmcnt(0): next tile landed; lgkmcnt(0): this tile's reads retired ->
    // safe to overwrite buf p at kt+1. Drain overlaps the compute above.
    __syncthreads();
  }
#undef STAGE

  // ---- LDS-transpose epilogue (aliases smem), 2 chunks of 64 rows ----
  const long rowg0 = bm * BM + wm * 64;
  const int colg0 = bn * BN + wn * 64;
#pragma unroll
  for (int c = 0; c < 2; ++c) {
    if (wm == c) {
#pragma unroll
      for (int i = 0; i < 4; ++i) {
        float as[4];
#pragma unroll
        for (int r = 0; r < 4; ++r) as[r] = asc[rowg0 + i * 16 + kb * 4 + r];
#pragma unroll
        for (int j = 0; j < 4; ++j) {
          const float ws = wsc[colg0 + j * 16 + rl];
#pragma unroll
          for (int r = 0; r < 4; ++r)
            tr[(i * 16 + kb * 4 + r) * 132 + wn * 64 + j * 16 + rl] =
                (float)acc[i][j][r] * as[r] * ws;
        }
      }
    }
    __syncthreads();
    // 256 threads x 8 float4 nt stores: 32 lanes cover 512B = 4 full lines
#pragma unroll
    for (int it = 0; it < 8; ++it) {
      const int idx = t + it * 256;   // 0..2047
      const int rl2 = idx >> 5;       // local row 0..63
      const int c4 = (idx & 31) * 4;  // col in floats
      const float4_t val = *(const float4_t*)(tr + rl2 * 132 + c4);
      __builtin_nontemporal_store(
          val, (float4_t*)(C + (bm * BM + c * 64 + rl2) * (long)N_DIM + bn * BN + c4));
    }
    __syncthreads();
  }
}

// ---------------------------------------------------------------------------
extern "C" void kernel_launch(void* const* d_in, const int* in_sizes, int n_in,
                              void* d_out, int out_size, void* d_ws, size_t ws_size,
                              hipStream_t stream) {
  const float* x = (const float*)d_in[0];  // [8,8192,1024] f32
  const float* w = (const float*)d_in[1];  // [1024,1024] f32
  float* out = (float*)d_out;              // [8,8192,1024] f32
  const int M = in_sizes[0] / K_DIM;       // 65536

  int8_t* qx = (int8_t*)d_ws;
  int8_t* qw = qx + (size_t)M * K_DIM;
  float* ascale = (float*)(qw + (size_t)N_DIM * K_DIM);
  float* wscale = ascale + M;

  fwht_quant_kernel<<<(M + 3) / 4, 256, 0, stream>>>(x, qx, ascale, M);
  wquant_kernel<<<N_DIM / 4, 256, 0, stream>>>(w, qw, wscale);
  gemm_i8_kernel<<<(M / BM) * (N_DIM / BN), 256, 0, stream>>>(qx, qw, ascale, wscale, out, M);
}